// Round 13
// baseline (577.506 us; speedup 1.0000x reference)
//
#include <hip/hip_runtime.h>
#include <hip/hip_bf16.h>

#define S_LEN 2048
#define D_DIM 64
#define QT    64
#define KT    64
#define NTHR  256
#define NTHR2 512
#define NKT   (S_LEN / KT)          // 32
#define NBLK  1024                  // 32 q-tiles * 32 bh
#define PROB_ELEMS 4194304LL        // 2*16*2048*64
#define QSC   0.1803368801f         // 0.125 * log2(e): exp(s/8) = 2^(acc)

typedef float        f32x4  __attribute__((ext_vector_type(4)));
typedef int          i32x4  __attribute__((ext_vector_type(4)));
typedef unsigned int u32x4  __attribute__((ext_vector_type(4)));
typedef short        bf16x8 __attribute__((ext_vector_type(8)));

__device__ __forceinline__ unsigned short f2bf(float f) {
    return __builtin_bit_cast(unsigned short, __float2bfloat16(f));
}
__device__ __forceinline__ int swzc(int row, int ch) {
    return ch ^ ((row ^ (row >> 3)) & 7);
}
__device__ __forceinline__ float4 scale4(float4 v, float s) {
    v.x *= s; v.y *= s; v.z *= s; v.w *= s; return v;
}
__device__ __forceinline__ u32x4 packbf(float4 a, float4 b) {
    u32x4 r;
    r[0] = (unsigned)f2bf(a.x) | ((unsigned)f2bf(a.y) << 16);
    r[1] = (unsigned)f2bf(a.z) | ((unsigned)f2bf(a.w) << 16);
    r[2] = (unsigned)f2bf(b.x) | ((unsigned)f2bf(b.y) << 16);
    r[3] = (unsigned)f2bf(b.z) | ((unsigned)f2bf(b.w) << 16);
    return r;
}
__device__ __forceinline__ unsigned cvtpk(float lo, float hi) {
    unsigned r;
    asm("v_cvt_pk_bf16_f32 %0, %1, %2" : "=v"(r) : "v"(lo), "v"(hi));
    return r;
}
__device__ __forceinline__ float vexp2(float x) {   // 2^x, native
    float r; asm("v_exp_f32 %0, %1" : "=v"(r) : "v"(x)); return r;
}
__device__ __forceinline__ void glds16(const unsigned* g, unsigned char* l) {
    __builtin_amdgcn_global_load_lds(
        (const __attribute__((address_space(1))) unsigned*)g,
        (__attribute__((address_space(3))) unsigned*)(void*)l, 16, 0, 0);
}
#define BC8(x) __builtin_bit_cast(bf16x8, (x))
#define MFMA(A, B, C) __builtin_amdgcn_mfma_f32_16x16x32_bf16((A), (B), (C), 0, 0, 0)

#define SFENCE() __builtin_amdgcn_sched_barrier(0)
#define WAITBAR(N)                                                          \
    SFENCE();                                                               \
    asm volatile("s_waitcnt vmcnt(" #N ")" ::: "memory");                   \
    SFENCE();                                                               \
    __builtin_amdgcn_s_barrier();                                           \
    SFENCE();

// -------------------------------------------------------------------------
__global__ void mask_probe_kernel(const unsigned int* __restrict__ m,
                                  int* __restrict__ flag) {
    unsigned int v = m[threadIdx.x];
    unsigned long long ok = __ballot(v <= 1u);
    if (threadIdx.x == 0) *flag = (ok == ~0ULL) ? 1 : 0;
}

// -------------------------------------------------------------------------
// One-shot prep (unchanged): K -> bf16 LDS-image tiles; V -> transposed
// [d][k] bf16 tile images. 8KB per (bh,kt) per tensor.
// -------------------------------------------------------------------------
#define KPART 524288
#define VPART 65536
__global__ __launch_bounds__(256)
void kv_prep(const float* __restrict__ Kg, const float* __restrict__ Vg,
             unsigned* __restrict__ Kbf, unsigned* __restrict__ Vtb) {
    int tid = blockIdx.x * 256 + threadIdx.x;
    if (tid < KPART) {
        int ch = tid & 7, rowg = tid >> 3;
        const float* src = Kg + (long long)rowg * D_DIM + ch * 8;
        float4 a = *(const float4*)src, b = *(const float4*)(src + 4);
        int bh = rowg >> 11, k = rowg & 2047, kt = k >> 6, row = k & 63;
        unsigned* dst = Kbf + ((unsigned)(bh * NKT + kt) << 11)
                            + row * 32 + swzc(row, ch) * 4;
        *(u32x4*)dst = packbf(a, b);
    } else if (tid < KPART + VPART) {
        int idx = tid - KPART;
        int d = idx & 63, kt = (idx >> 6) & 31, bh = idx >> 11;
        const float* vb = Vg + (long long)(bh * S_LEN + kt * KT) * D_DIM + d;
        unsigned* tile = Vtb + ((unsigned)(bh * NKT + kt) << 11) + d * 32;
        #pragma unroll
        for (int ci = 0; ci < 8; ++ci) {
            u32x4 o;
            #pragma unroll
            for (int s = 0; s < 4; ++s) {
                float lo = vb[(ci * 8 + 2 * s) * D_DIM];
                float hi = vb[(ci * 8 + 2 * s + 1) * D_DIM];
                o[s] = (unsigned)f2bf(lo) | ((unsigned)f2bf(hi) << 16);
            }
            *(u32x4*)(tile + swzc(d, ci) * 4) = o;
        }
    }
}

// ==================== 512-thread main kernel macros ====================
// wave w = t>>6: wq = w>>1 (q-group of 16 rows), wk = w&1 (k-half of 32).
#define GK2(KS, KTV)                                                        \
    { glds16(Kbf + ktile0 + (unsigned)(KTV) * 2048u + fsrc, (KS) + fdst); }
#define GV2(VT, KTV)                                                        \
    { glds16(Vtb + ktile0 + (unsigned)(KTV) * 2048u + fsrc, (VT) + fdst); }

#define PM2(MI, MU, KTV)                                                    \
    { if (mask32) {                                                         \
        MI[0] = *(const i32x4*)(maskI + rowoff + (unsigned)(KTV) * KT + colbase);      \
        MI[1] = *(const i32x4*)(maskI + rowoff + (unsigned)(KTV) * KT + colbase + 16); \
      } else {                                                              \
        MU[0] = *(const unsigned*)(maskB + rowoff + (unsigned)(KTV) * KT + colbase);      \
        MU[1] = *(const unsigned*)(maskB + rowoff + (unsigned)(KTV) * KT + colbase + 16); \
      } }

#define BB2(DST, MI, MU)                                                    \
    { unsigned bz_ = 0u;                                                    \
      if (mask32) {                                                         \
        bz_ |=  (MI[0][0]?1u:0u)|(MI[0][1]?2u:0u)|(MI[0][2]?4u:0u)|(MI[0][3]?8u:0u);      \
        bz_ |= ((MI[1][0]?1u:0u)|(MI[1][1]?2u:0u)|(MI[1][2]?4u:0u)|(MI[1][3]?8u:0u))<<4;  \
      } else {                                                              \
        unsigned m0_ = MU[0], m1_ = MU[1];                                  \
        bz_ |=  ((m0_&0xffu)?1u:0u)|((m0_&0xff00u)?2u:0u)|                  \
                ((m0_&0xff0000u)?4u:0u)|((m0_&0xff000000u)?8u:0u);          \
        bz_ |= (((m1_&0xffu)?1u:0u)|((m1_&0xff00u)?2u:0u)|                  \
                ((m1_&0xff0000u)?4u:0u)|((m1_&0xff000000u)?8u:0u))<<4;      \
      }                                                                     \
      (DST) = bz_; }

#define NP1(KS, BITS)                                                       \
    { unsigned bb_ = (BITS);                                                \
      _Pragma("unroll")                                                     \
      for (int n_ = 0; n_ < 2; ++n_) {                                      \
        int rowk = wk * 32 + n_ * 16 + c;                                   \
        bf16x8 kf0 = *(const bf16x8*)((KS) + rowk * 128 + swzc(rowk, g) * 16);     \
        bf16x8 kf1 = *(const bf16x8*)((KS) + rowk * 128 + swzc(rowk, 4 + g) * 16); \
        f32x4 acc = {0.f, 0.f, 0.f, 0.f};                                   \
        acc = MFMA(kf0, qf0, acc); acc = MFMA(kf1, qf1, acc);               \
        unsigned mb_ = bb_ >> (n_ * 4);                                     \
        psum += (mb_ & 1u) ? 0.f : vexp2(acc[0]);                           \
        psum += (mb_ & 2u) ? 0.f : vexp2(acc[1]);                           \
        psum += (mb_ & 4u) ? 0.f : vexp2(acc[2]);                           \
        psum += (mb_ & 8u) ? 0.f : vexp2(acc[3]);                           \
      } }

#define NP2(KS, VT, BITS, KTV)                                              \
    { unsigned bb_ = (BITS);                                                \
      _Pragma("unroll")                                                     \
      for (int n_ = 0; n_ < 2; ++n_) {                                      \
        int rowk = wk * 32 + n_ * 16 + c;                                   \
        bf16x8 kf0 = *(const bf16x8*)((KS) + rowk * 128 + swzc(rowk, g) * 16);     \
        bf16x8 kf1 = *(const bf16x8*)((KS) + rowk * 128 + swzc(rowk, 4 + g) * 16); \
        f32x4 acc = {0.f, 0.f, 0.f, 0.f};                                   \
        acc = MFMA(kf0, qf0, acc); acc = MFMA(kf1, qf1, acc);               \
        unsigned mb_ = bb_ >> (n_ * 4);                                     \
        f32x4 ev;                                                           \
        ev[0] = (mb_ & 1u) ? 0.f : vexp2(acc[0]) * rinv;                    \
        ev[1] = (mb_ & 2u) ? 0.f : vexp2(acc[1]) * rinv;                    \
        ev[2] = (mb_ & 4u) ? 0.f : vexp2(acc[2]) * rinv;                    \
        ev[3] = (mb_ & 8u) ? 0.f : vexp2(acc[3]) * rinv;                    \
        unsigned idx_ = rowoff + (unsigned)(KTV) * KT + colbase + n_ * 16;  \
        *(f32x4*)(attnOut + idx_) = ev;                                     \
        uint2 pk_; pk_.x = cvtpk(ev[0], ev[1]); pk_.y = cvtpk(ev[2], ev[3]);\
        int k0_ = wk * 32 + n_ * 16 + 4 * g;                                \
        *(uint2*)(Ps + ql * 128 + swzc(ql, k0_ >> 3) * 16 + (k0_ & 7) * 2) = pk_; \
      }                                                                     \
      { bf16x8 pa_ = *(const bf16x8*)(Ps + ql * 128 + swzc(ql, wk * 4 + g) * 16); \
        __builtin_amdgcn_s_setprio(1);                                      \
        _Pragma("unroll")                                                   \
        for (int df_ = 0; df_ < 4; ++df_) {                                 \
            int d_ = df_ * 16 + c;                                          \
            bf16x8 vb_ = *(const bf16x8*)((VT) + d_ * 128 + swzc(d_, wk * 4 + g) * 16); \
            pacc[df_] = MFMA(pa_, vb_, pacc[df_]);                          \
        }                                                                   \
        __builtin_amdgcn_s_setprio(0); } }

// -------------------------------------------------------------------------
// Main kernel: 512 threads (8 waves: 4 q-groups x 2 k-halves), 1024 blocks,
// LDS 40KB -> 4 blocks/CU -> 32 waves/CU cap. Counted-vmcnt dbuf rounds.
// -------------------------------------------------------------------------
__global__ __launch_bounds__(NTHR2, 8)
void attn_fused_glds2(const float* __restrict__ Qg,
                      const unsigned* __restrict__ Kbf,
                      const unsigned* __restrict__ Vtb,
                      const unsigned char* __restrict__ maskB,
                      const int* __restrict__ flagp,
                      unsigned char* __restrict__ bitsWS,
                      float* __restrict__ attnOut, float* __restrict__ probOut) {
    __shared__ unsigned char sm[40960];
    unsigned char* Ks0 = sm;
    unsigned char* Ks1 = sm + 8192;
    unsigned char* Vt0 = sm + 16384;
    unsigned char* Vt1 = sm + 24576;
    unsigned char* Ps  = sm + 32768;

    const int t = threadIdx.x;
    const int lane = t & 63, w = t >> 6;
    const int c = lane & 15, g = (lane >> 4) & 3;
    const int wq = w >> 1, wk = w & 1;

    const int orig = blockIdx.x;
    const int virt = (orig & 7) * 128 + (orig >> 3);   // XCD swizzle
    const int qt = virt & 31, bh = virt >> 5;
    const int mask32 = *flagp;
    const int* maskI = (const int*)maskB;

    const int qrowbase = bh * S_LEN + qt * QT;
    const int ql = wq * 16 + c;
    const unsigned rowoff = (unsigned)(qrowbase + ql) * (unsigned)S_LEN;
    const unsigned colbase = (unsigned)(wk * 32 + 4 * g);
    const unsigned bitbase = (unsigned)virt * (NKT * NTHR2) + (unsigned)t;
    const unsigned ktile0 = (unsigned)(bh * NKT) << 11;

    const int fsrc = t * 4;              // u32 idx into 8KB tile image
    const int fdst = (t & ~63) * 16;     // wave-uniform LDS byte offset

    // ---- stage Q (pre-scaled by 0.125*log2e) into Ps, keep fragments ----
    {
        int row = t >> 3, ch = t & 7;
        const float* src = Qg + (qrowbase + row) * D_DIM + ch * 8;
        float4 a = *(const float4*)src, b = *(const float4*)(src + 4);
        *(u32x4*)(Ps + row * 128 + swzc(row, ch) * 16) =
            packbf(scale4(a, QSC), scale4(b, QSC));
    }
    __syncthreads();
    bf16x8 qf0 = *(const bf16x8*)(Ps + ql * 128 + swzc(ql, g) * 16);
    bf16x8 qf1 = *(const bf16x8*)(Ps + ql * 128 + swzc(ql, 4 + g) * 16);

    // =================== PHASE 1: rowsum + mask bits ===================
    float psum = 0.f;
    {
        i32x4 mAi[2], mBi[2];
        unsigned mAu[2], mBu[2], bA, bB;
        GK2(Ks0, 0)
        PM2(mAi, mAu, 0)
        WAITBAR(0)

        for (int j = 0; j < NKT / 2; ++j) {
            const int ktA = 2 * j, ktB = 2 * j + 1;
            GK2(Ks1, ktB)
            PM2(mBi, mBu, ktB)
            SFENCE();
            BB2(bA, mAi, mAu)
            NP1(Ks0, bA)
            bitsWS[bitbase + (unsigned)ktA * NTHR2] = (unsigned char)bA;
            WAITBAR(1)                   // retire glds+mask(B); leave bits store

            if (j + 1 < NKT / 2) {
                GK2(Ks0, ktA + 2)
                PM2(mAi, mAu, ktA + 2)
            }
            SFENCE();
            BB2(bB, mBi, mBu)
            NP1(Ks1, bB)
            bitsWS[bitbase + (unsigned)ktB * NTHR2] = (unsigned char)bB;
            WAITBAR(1)
        }
    }
    // cross-g, then cross-k-half rowsum via LDS (Ps area, pre-overwrite)
    {
        float s = psum;
        s += __shfl_xor(s, 16, 64);
        s += __shfl_xor(s, 32, 64);
        if (lane < 16) ((float*)Ps)[w * 16 + c] = s;
    }
    __syncthreads();
    const float rinv = 1.0f / (((const float*)Ps)[(wq * 2 + 0) * 16 + c] +
                               ((const float*)Ps)[(wq * 2 + 1) * 16 + c]);

    // =================== PHASE 2: attn + PV ===================
    f32x4 pacc[4];
    #pragma unroll
    for (int d = 0; d < 4; ++d) pacc[d] = (f32x4){0.f, 0.f, 0.f, 0.f};
    {
        unsigned bA, bB;
        GK2(Ks0, 0) GV2(Vt0, 0)
        bA = (unsigned)bitsWS[bitbase];
        WAITBAR(0)

        for (int j = 0; j < NKT / 2; ++j) {
            const int ktA = 2 * j, ktB = 2 * j + 1;
            GK2(Ks1, ktB) GV2(Vt1, ktB)
            bB = (unsigned)bitsWS[bitbase + (unsigned)ktB * NTHR2];
            SFENCE();
            NP2(Ks0, Vt0, bA, ktA)
            WAITBAR(2)                   // retire gldsK,gldsV,bits; leave 2 stores

            if (j + 1 < NKT / 2) {
                GK2(Ks0, ktA + 2) GV2(Vt0, ktA + 2)
                bA = (unsigned)bitsWS[bitbase + (unsigned)(ktA + 2) * NTHR2];
            }
            SFENCE();
            NP2(Ks1, Vt1, bB, ktB)
            WAITBAR(2)
        }
    }

    // ---- cross-k-half pacc reduce + prob store ----
    __syncthreads();
    if (wk == 1) {
        #pragma unroll
        for (int df = 0; df < 4; ++df)
            *(f32x4*)(sm + wq * 4096 + lane * 64 + df * 16) = pacc[df];
    }
    __syncthreads();
    if (wk == 0) {
        #pragma unroll
        for (int df = 0; df < 4; ++df) {
            f32x4 o = pacc[df] +
                *(const f32x4*)(sm + wq * 4096 + lane * 64 + df * 16);
            #pragma unroll
            for (int r = 0; r < 4; ++r) {
                int qe = qrowbase + wq * 16 + g * 4 + r;
                probOut[(long long)qe * D_DIM + df * 16 + c] = o[r];
            }
        }
    }
}

// -------------------------------------------------------------------------
// Fallback (R12 256-thread register-staging kernel) if ws too small.
// -------------------------------------------------------------------------
#define GP1_TILE(KS, BITS)                                                  \
    { unsigned bb = (BITS);                                                 \
      _Pragma("unroll")                                                     \
      for (int n = 0; n < 4; ++n) {                                         \
        int rowk = n * 16 + c;                                              \
        bf16x8 kf0 = *(const bf16x8*)((KS) + rowk * 128 + swzc(rowk, g) * 16);     \
        bf16x8 kf1 = *(const bf16x8*)((KS) + rowk * 128 + swzc(rowk, 4 + g) * 16); \
        f32x4 acc = {0.f, 0.f, 0.f, 0.f};                                   \
        acc = MFMA(kf0, qf0, acc); acc = MFMA(kf1, qf1, acc);               \
        unsigned mb = bb >> (n * 4);                                        \
        psum += (mb & 1u) ? 0.f : __expf(acc[0]);                           \
        psum += (mb & 2u) ? 0.f : __expf(acc[1]);                           \
        psum += (mb & 4u) ? 0.f : __expf(acc[2]);                           \
        psum += (mb & 8u) ? 0.f : __expf(acc[3]);                           \
      } }

#define GP2_TILE(KS, VT, BITS, KTV)                                         \
    { unsigned bb = (BITS);                                                 \
      _Pragma("unroll")                                                     \
      for (int n = 0; n < 4; ++n) {                                         \
        int rowk = n * 16 + c;                                              \
        bf16x8 kf0 = *(const bf16x8*)((KS) + rowk * 128 + swzc(rowk, g) * 16);     \
        bf16x8 kf1 = *(const bf16x8*)((KS) + rowk * 128 + swzc(rowk, 4 + g) * 16); \
        f32x4 acc = {0.f, 0.f, 0.f, 0.f};                                   \
        acc = MFMA(kf0, qf0, acc); acc = MFMA(kf1, qf1, acc);               \
        unsigned mb = bb >> (n * 4);                                        \
        f32x4 ev;                                                           \
        ev[0] = (mb & 1u) ? 0.f : __expf(acc[0]) * rinv;                    \
        ev[1] = (mb & 2u) ? 0.f : __expf(acc[1]) * rinv;                    \
        ev[2] = (mb & 4u) ? 0.f : __expf(acc[2]) * rinv;                    \
        ev[3] = (mb & 8u) ? 0.f : __expf(acc[3]) * rinv;                    \
        unsigned idx0 = rowoff + (unsigned)((KTV) * KT + n * 16 + 4 * g);   \
        *(f32x4*)(attnOut + idx0) = ev;                                     \
        uint2 pkv; pkv.x = cvtpk(ev[0], ev[1]); pkv.y = cvtpk(ev[2], ev[3]);\
        int kloc = n * 16 + 4 * g;                                          \
        *(uint2*)(Ps + ql * 128 + swzc(ql, kloc >> 3) * 16 + (kloc & 7) * 2) = pkv; \
      }                                                                     \
      { bf16x8 pa0 = *(const bf16x8*)(Ps + ql * 128 + swzc(ql, g) * 16);    \
        bf16x8 pa1 = *(const bf16x8*)(Ps + ql * 128 + swzc(ql, 4 + g) * 16);\
        __builtin_amdgcn_s_setprio(1);                                      \
        _Pragma("unroll")                                                   \
        for (int df = 0; df < 4; ++df) {                                    \
            int d = df * 16 + c;                                            \
            bf16x8 vb0 = *(const bf16x8*)((VT) + d * 128 + swzc(d, g) * 16);     \
            bf16x8 vb1 = *(const bf16x8*)((VT) + d * 128 + swzc(d, 4 + g) * 16); \
            pacc[df] = MFMA(pa0, vb0, pacc[df]);                            \
            pacc[df] = MFMA(pa1, vb1, pacc[df]);                            \
        }                                                                   \
        __builtin_amdgcn_s_setprio(0); } }

#define FB_MBITS(DST, KTV)                                                  \
    { unsigned bz_ = 0u;                                                    \
      _Pragma("unroll")                                                     \
      for (int n_ = 0; n_ < 4; ++n_) {                                      \
        unsigned idx_ = rowoff + (unsigned)((KTV) * KT + n_ * 16 + 4 * g);  \
        if (mask32) {                                                       \
            i32x4 m4_ = *(const i32x4*)(maskI + idx_);                      \
            bz_ |= ((m4_[0] ? 1u : 0u) | (m4_[1] ? 2u : 0u) |               \
                    (m4_[2] ? 4u : 0u) | (m4_[3] ? 8u : 0u)) << (n_ * 4);   \
        } else {                                                            \
            unsigned mb_ = *(const unsigned*)(maskB + idx_);                \
            bz_ |= (((mb_ & 0xffu) ? 1u : 0u) | ((mb_ & 0xff00u) ? 2u : 0u) | \
                    ((mb_ & 0xff0000u) ? 4u : 0u) |                         \
                    ((mb_ & 0xff000000u) ? 8u : 0u)) << (n_ * 4);           \
        } }                                                                 \
      (DST) = bz_; }

#define FB_BITS2(DST, KTV)                                                  \
    { if (useWS) (DST) = (unsigned)bitsWS[bitbase + (unsigned)(KTV)*NTHR];  \
      else FB_MBITS(DST, KTV) }

#define FB_LOAD_K(KP, KTV)                                                  \
    { _Pragma("unroll")                                                     \
      for (int i = 0; i < 2; ++i) {                                         \
        int flat = i * NTHR + t, row = flat >> 3, ch = flat & 7;            \
        const float* src = Kg + (kbase + (KTV) * KT + row) * D_DIM + ch * 8;\
        float4 a = *(const float4*)src, b = *(const float4*)(src + 4);      \
        KP[i] = packbf(a, b);                                               \
      } }
#define FB_STAGE_K(KS, KP)                                                  \
    { _Pragma("unroll")                                                     \
      for (int i = 0; i < 2; ++i) {                                         \
        int flat = i * NTHR + t, row = flat >> 3, ch = flat & 7;            \
        *(u32x4*)((KS) + row * 128 + swzc(row, ch) * 16) = KP[i];           \
      } }
#define FB_LOAD_V(VP, KTV)                                                  \
    { const float* src = Vg + (kbase + (KTV) * KT + k0v) * D_DIM + dgv * 8; \
      float4 a = *(const float4*)src, b = *(const float4*)(src + 4);        \
      float4 e4 = *(const float4*)(src + D_DIM);                            \
      float4 f4 = *(const float4*)(src + D_DIM + 4);                        \
      VP[0] = (unsigned)f2bf(a.x) | ((unsigned)f2bf(e4.x) << 16);           \
      VP[1] = (unsigned)f2bf(a.y) | ((unsigned)f2bf(e4.y) << 16);           \
      VP[2] = (unsigned)f2bf(a.z) | ((unsigned)f2bf(e4.z) << 16);           \
      VP[3] = (unsigned)f2bf(a.w) | ((unsigned)f2bf(e4.w) << 16);           \
      VP[4] = (unsigned)f2bf(b.x) | ((unsigned)f2bf(f4.x) << 16);           \
      VP[5] = (unsigned)f2bf(b.y) | ((unsigned)f2bf(f4.y) << 16);           \
      VP[6] = (unsigned)f2bf(b.z) | ((unsigned)f2bf(f4.z) << 16);           \
      VP[7] = (unsigned)f2bf(b.w) | ((unsigned)f2bf(f4.w) << 16); }
#define FB_STAGE_V(VT, VP)                                                  \
    { _Pragma("unroll")                                                     \
      for (int jj = 0; jj < 8; ++jj) {                                      \
        int d = dgv * 8 + jj;                                               \
        *(unsigned*)((VT) + d * 128 + swzc(d, k0v >> 3) * 16 + (k0v & 7) * 2) = VP[jj]; \
      } }

__global__ __launch_bounds__(NTHR, 4)
void attn_fused_reg(const float* __restrict__ Qg, const float* __restrict__ Kg,
                    const float* __restrict__ Vg,
                    const unsigned char* __restrict__ maskB,
                    const int* __restrict__ flagp,
                    unsigned short* __restrict__ bitsWS, int useWS,
                    float* __restrict__ attnOut, float* __restrict__ probOut) {
    __shared__ unsigned char sm[40960];
    unsigned char* Ks0 = sm;
    unsigned char* Ks1 = sm + 8192;
    unsigned char* Vt0 = sm + 16384;
    unsigned char* Vt1 = sm + 24576;
    unsigned char* Ps  = sm + 32768;

    const int t = threadIdx.x;
    const int lane = t & 63, w = t >> 6, c = lane & 15, g = lane >> 4;
    (void)lane;

    const int orig = blockIdx.x;
    const int virt = (orig & 7) * 128 + (orig >> 3);
    const int qt = virt & 31, bh = virt >> 5;
    const int mask32 = *flagp;
    const int* maskI = (const int*)maskB;

    const int qrowbase = bh * S_LEN + qt * QT;
    const int kbase = bh * S_LEN;
    const int ql = w * 16 + c;
    const unsigned rowoff = (unsigned)(qrowbase + ql) * (unsigned)S_LEN;
    const unsigned bitbase = (unsigned)virt * NKT * NTHR + (unsigned)t;
    const int dgv = t & 7, k0v = (t >> 3) * 2;

    #pragma unroll
    for (int i = 0; i < 2; ++i) {
        int flat = i * NTHR + t, row = flat >> 3, ch = flat & 7;
        const float* src = Qg + (qrowbase + row) * D_DIM + ch * 8;
        float4 a = *(const float4*)src, b = *(const float4*)(src + 4);
        *(u32x4*)(Ps + row * 128 + swzc(row, ch) * 16) =
            packbf(scale4(a, 0.125f), scale4(b, 0.125f));
    }
    __syncthreads();
    bf16x8 qf0 = *(const bf16x8*)(Ps + ql * 128 + swzc(ql, g) * 16);
    bf16x8 qf1 = *(const bf16x8*)(Ps + ql * 128 + swzc(ql, 4 + g) * 16);
    __syncthreads();

    float psum = 0.f;
    u32x4 kpA[2], kpB[2];
    unsigned bA, bB;
    FB_LOAD_K(kpA, 0)
    FB_MBITS(bA, 0)

    for (int j = 0; j < NKT / 2; ++j) {
        const int ktA = 2 * j, ktB = 2 * j + 1;
        FB_STAGE_K(Ks0, kpA)
        FB_LOAD_K(kpB, ktB)
        FB_MBITS(bB, ktB)
        __syncthreads();
        GP1_TILE(Ks0, bA)
        if (useWS) bitsWS[bitbase + (unsigned)ktA * NTHR] = (unsigned short)bA;
        FB_STAGE_K(Ks1, kpB)
        if (j + 1 < NKT / 2) {
            FB_LOAD_K(kpA, ktA + 2)
            FB_MBITS(bA, ktA + 2)
        }
        __syncthreads();
        GP1_TILE(Ks1, bB)
        if (useWS) bitsWS[bitbase + (unsigned)ktB * NTHR] = (unsigned short)bB;
    }

    float s = psum;
    s += __shfl_xor(s, 16, 64);
    s += __shfl_xor(s, 32, 64);
    const float rinv = 1.0f / s;

    f32x4 pacc[4];
    #pragma unroll
    for (int d = 0; d < 4; ++d) pacc[d] = (f32x4){0.f, 0.f, 0.f, 0.f};

    unsigned vpA[8], vpB[8];
    FB_LOAD_K(kpA, 0)
    FB_LOAD_V(vpA, 0)
    FB_BITS2(bA, 0)
    __syncthreads();

    for (int j = 0; j < NKT / 2; ++j) {
        const int ktA = 2 * j, ktB = 2 * j + 1;
        FB_STAGE_K(Ks0, kpA)
        FB_STAGE_V(Vt0, vpA)
        FB_LOAD_K(kpB, ktB)
        FB_LOAD_V(vpB, ktB)
        FB_BITS2(bB, ktB)
        __syncthreads();
        GP2_TILE(Ks0, Vt0, bA, ktA)
        FB_STAGE_K(Ks1, kpB)
        FB_STAGE_V(Vt1, vpB)
        if (j + 1 < NKT / 2) {
            FB_LOAD_K(kpA, ktA + 2)
            FB_LOAD_V(vpA, ktA + 2)
            FB_BITS2(bA, ktA + 2)
        }
        __syncthreads();
        GP2_TILE(Ks1, Vt1, bB, ktB)
    }

    #pragma unroll
    for (int df = 0; df < 4; ++df)
        #pragma unroll
        for (int r = 0; r < 4; ++r) {
            int qe = w * 16 + g * 4 + r;
            probOut[(long long)(qrowbase + qe) * D_DIM + df * 16 + c] = pacc[df][r];
        }
}

// -------------------------------------------------------------------------
extern "C" void kernel_launch(void* const* d_in, const int* in_sizes, int n_in,
                              void* d_out, int out_size, void* d_ws, size_t ws_size,
                              hipStream_t stream) {
    const float* Q = (const float*)d_in[0];
    const float* K = (const float*)d_in[1];
    const float* V = (const float*)d_in[2];
    const unsigned char* mask = (const unsigned char*)d_in[3];

    float* prob = (float*)d_out;
    float* attn = (float*)d_out + PROB_ELEMS;

    const size_t bits_bytes = 16777216ull;  // u8 x 1024blk x 32kt x 512thr
    const size_t kbf_bytes  = 8388608ull;   // per tensor
    int* flag = (int*)d_ws;
    unsigned char*  bits8  = (unsigned char*)((char*)d_ws + 256);
    unsigned short* bits16 = (unsigned short*)((char*)d_ws + 256);
    unsigned* Kbf = (unsigned*)((char*)d_ws + 256 + bits_bytes);
    unsigned* Vtb = (unsigned*)((char*)d_ws + 256 + bits_bytes + kbf_bytes);

    const int useWS   = (ws_size >= 256 + bits_bytes) ? 1 : 0;
    const int usePrep = (ws_size >= 256 + bits_bytes + 2 * kbf_bytes) ? 1 : 0;

    mask_probe_kernel<<<1, 64, 0, stream>>>((const unsigned int*)mask, flag);
    if (usePrep && useWS) {
        kv_prep<<<(KPART + VPART) / 256, 256, 0, stream>>>(K, V, Kbf, Vtb);
        attn_fused_glds2<<<NBLK, NTHR2, 0, stream>>>(Q, Kbf, Vtb, mask, flag,
                                                     bits8, attn, prob);
    } else {
        attn_fused_reg<<<NBLK, NTHR, 0, stream>>>(Q, K, V, mask, flag,
                                                  bits16, useWS, attn, prob);
    }
}